// Round 3
// baseline (589.599 us; speedup 1.0000x reference)
//
#include <hip/hip_runtime.h>
#include <math.h>

// NCE loss: N=16384 rows x D=4096, fp32.
// out = mean_i( logsumexp(logits_i/alpha) - logits_i[argmax(labels_i)]/alpha )
// Streaming 512 MB (labels+logits); mask untouched. HBM floor ~81 us.
//
// R2 structure: one wave per row (64 elems/lane/stream), NO barriers, NO LDS,
// online logsumexp so only 8+8 vf4 live at a time (~5 waves/SIMD occupancy),
// shuffle-only reductions, nontemporal streaming loads.

typedef float vf4 __attribute__((ext_vector_type(4)));

constexpr int Dk    = 4096;
constexpr int BLOCK = 256;            // 4 waves = 4 rows per block
constexpr int ROWS_PER_BLOCK = 4;

__global__ __launch_bounds__(BLOCK) void nce_main(
    const float* __restrict__ labels, const float* __restrict__ logits,
    const float* __restrict__ alpha, float* __restrict__ bins)
{
    const int lane = threadIdx.x & 63;
    const int wave = threadIdx.x >> 6;
    const int row  = blockIdx.x * ROWS_PER_BLOCK + wave;
    const size_t base = (size_t)row * Dk;
    const vf4* g4 = reinterpret_cast<const vf4*>(logits + base);
    const vf4* l4 = reinterpret_cast<const vf4*>(labels + base);
    const float ia = 1.0f / alpha[0];

    // Online-logsumexp state (per lane) + label argmax triple.
    float m = -INFINITY, s = 0.0f;
    float lmax = -INFINITY, lval = 0.0f;
    int   lidx = 0x7fffffff;

#pragma unroll 1                     // two halves; keeps VGPRs ~<100
    for (int half = 0; half < 2; ++half) {
        const int c0 = half * 8;
        vf4 g[8], l[8];
        // 16 x 16B nontemporal loads issued back-to-back (256 B/lane in flight).
#pragma unroll
        for (int j = 0; j < 8; ++j)
            g[j] = __builtin_nontemporal_load(g4 + lane + 64 * (c0 + j));
#pragma unroll
        for (int j = 0; j < 8; ++j)
            l[j] = __builtin_nontemporal_load(l4 + lane + 64 * (c0 + j));

#pragma unroll
        for (int j = 0; j < 8; ++j) {
            // logsumexp online update, one rescale per 4 elements
            const float c4 = fmaxf(fmaxf(g[j][0], g[j][1]), fmaxf(g[j][2], g[j][3]));
            const float mn = fmaxf(m, c4);
            const float e0 = __expf((g[j][0] - mn) * ia);
            const float e1 = __expf((g[j][1] - mn) * ia);
            const float e2 = __expf((g[j][2] - mn) * ia);
            const float e3 = __expf((g[j][3] - mn) * ia);
            s = s * __expf((m - mn) * ia) + ((e0 + e1) + (e2 + e3));
            m = mn;
            // label argmax (first-occurrence tie-break, matches jnp.argmax)
#pragma unroll
            for (int e = 0; e < 4; ++e) {
                const float le  = l[j][e];
                const int   idx = 4 * (lane + 64 * (c0 + j)) + e;
                if (le > lmax || (le == lmax && idx < lidx)) {
                    lmax = le; lidx = idx; lval = g[j][e];
                }
            }
        }
    }

    // Wave-wide max of m (all lanes get M), rescale local s once.
    float M = m;
#pragma unroll
    for (int off = 1; off < 64; off <<= 1)
        M = fmaxf(M, __shfl_xor(M, off));
    s *= __expf((m - M) * ia);

    // Wave reduce: sum + argmax triple (lane 0 ends up with the result).
#pragma unroll
    for (int off = 32; off; off >>= 1) {
        s += __shfl_down(s, off);
        const float om = __shfl_down(lmax, off);
        const int   oi = __shfl_down(lidx, off);
        const float ov = __shfl_down(lval, off);
        if (om > lmax || (om == lmax && oi < lidx)) { lmax = om; lidx = oi; lval = ov; }
    }

    if (lane == 0)
        bins[row] = (M - lval) * ia + logf(s);
}

// Reduce 16384 per-row values -> mean. One block.
__global__ __launch_bounds__(BLOCK) void nce_finalize(
    const float* __restrict__ bins, float* __restrict__ out, int n, float inv_n)
{
    const int t = threadIdx.x;
    float v = 0.0f;
    for (int i = t; i < n; i += BLOCK) v += bins[i];
#pragma unroll
    for (int off = 32; off; off >>= 1) v += __shfl_down(v, off);
    __shared__ float s_w[BLOCK / 64];
    if ((t & 63) == 0) s_w[t >> 6] = v;
    __syncthreads();
    if (t == 0) out[0] = (s_w[0] + s_w[1] + s_w[2] + s_w[3]) * inv_n;
}

extern "C" void kernel_launch(void* const* d_in, const int* in_sizes, int n_in,
                              void* d_out, int out_size, void* d_ws, size_t ws_size,
                              hipStream_t stream) {
    const float* labels = (const float*)d_in[0];
    const float* logits = (const float*)d_in[1];
    // d_in[2] = mask (unused by the reference math)
    const float* alpha  = (const float*)d_in[3];
    float* out  = (float*)d_out;
    float* bins = (float*)d_ws;   // N floats = 64 KB scratch

    const int N = in_sizes[0] / Dk;  // 16384

    nce_main<<<N / ROWS_PER_BLOCK, BLOCK, 0, stream>>>(labels, logits, alpha, bins);
    nce_finalize<<<1, BLOCK, 0, stream>>>(bins, out, N, 1.0f / (float)N);
}